// Round 11
// baseline (176.198 us; speedup 1.0000x reference)
//
#include <hip/hip_runtime.h>
#include <stdint.h>

// Problem constants (from reference setup_inputs)
#define BATCH 4096
#define ISZ   512
#define OSZ   512
#define KDIM  4096           // contraction dim: k = i*8 + d

// GEMM tiling (R14 = R12 gemm + fused last-block split-K reduction).
// History: R7/R12 (identical source) measured 96.0 AND 101.8 -> noise
// band +-3us. R8/R10/R11 schedule surgeries and R13 (32x32x16 core,
// 103.7) all within-noise-or-worse: gemm internals are at this
// structure's local optimum (matches m131-m141). R14 attacks the
// SERIAL TAIL instead: reduce_k could only start after the LAST gemm
// block -> its ~6-8us (dispatch gap + 16.8MB read + 8.4MB write) was
// fully serialized. Now each output tile's 4 z-blocks count arrivals
// (threadfence-reduction pattern); the last one reduces -> early tiles'
// reductions overlap still-computing blocks, reduce_k dispatch deleted.
#define TM 128
#define TN 128
#define BK 64
#define SPLITK 4
#define NTILEY (OSZ / TN)    // 4
#define NTILES ((BATCH / TM) * NTILEY)   // 128 output tiles

typedef __bf16 bf16x8 __attribute__((ext_vector_type(8)));
typedef float  f32x4  __attribute__((ext_vector_type(4)));

__device__ __forceinline__ unsigned short f2bf(float f) {
    uint32_t u = __float_as_uint(f);
    u = (u + 0x7FFFu + ((u >> 16) & 1u)) >> 16;
    return (unsigned short)u;
}

// prep: blocks [0,2048) coef fp32 [O][I][D] -> bf16 [O][K] (k-contiguous);
// blocks [2048,4096): jacobi8(tanh(x)) -> A bf16 [BATCH][KDIM], 4 x/thread.
// Jacobi computed ONCE (R7 win). R14: block 0 also zeroes the 128
// split-K arrival counters — MUST be per-launch (harness poison-fills
// the workspace between iterations); the prep->gemm dispatch boundary
// orders the zeroing before any gemm atomicAdd.
#define NB_CONV 2048         // (OSZ*KDIM/4) / 256
#define NB_JAC  2048         // (BATCH*ISZ/4) / 256
__global__ __launch_bounds__(256) void prep(
    const float* __restrict__ coef, unsigned short* __restrict__ coefb,
    const float* __restrict__ X,    unsigned short* __restrict__ Ab,
    int* __restrict__ cnt)
{
    const int b = blockIdx.x;
    if (b == 0 && threadIdx.x < NTILES) cnt[threadIdx.x] = 0;
    if (b < NB_CONV) {
        int idx = b * 256 + threadIdx.x;
        float4 v = reinterpret_cast<const float4*>(coef)[idx];
        uint2 o;
        o.x = (uint32_t)f2bf(v.x) | ((uint32_t)f2bf(v.y) << 16);
        o.y = (uint32_t)f2bf(v.z) | ((uint32_t)f2bf(v.w) << 16);
        reinterpret_cast<uint2*>(coefb)[idx] = o;
    } else {
        int idx = (b - NB_CONV) * 256 + threadIdx.x;   // over [BATCH*ISZ/4]
        float4 xv = reinterpret_cast<const float4*>(X)[idx];
        const float xs[4] = {xv.x, xv.y, xv.z, xv.w};
        #pragma unroll
        for (int j = 0; j < 4; ++j) {
            // tanh(x) = 1 - 2/(exp(2x)+1); err ~1e-6 << bf16 ulp
            float e  = __expf(2.0f * xs[j]);
            float t  = 1.0f - 2.0f * __builtin_amdgcn_rcpf(e + 1.0f);
            float p0 = 1.0f;
            float p1 = 2.0f * t;
            float p2 = (1.875f     * t) * p1 - 0.75f       * p0;
            float p3 = (1.8666667f * t) * p2 - 0.8f        * p1;
            float p4 = (1.875f     * t) * p3 - 0.83333333f * p2;
            float p5 = (1.8857143f * t) * p4 - 0.85714287f * p3;
            float p6 = (1.8958333f * t) * p5 - 0.875f      * p4;
            float p7 = (1.9047619f * t) * p6 - 0.88888889f * p5;
            uint4 o;
            o.x = (uint32_t)f2bf(p0) | ((uint32_t)f2bf(p1) << 16);
            o.y = (uint32_t)f2bf(p2) | ((uint32_t)f2bf(p3) << 16);
            o.z = (uint32_t)f2bf(p4) | ((uint32_t)f2bf(p5) << 16);
            o.w = (uint32_t)f2bf(p6) | ((uint32_t)f2bf(p7) << 16);
            reinterpret_cast<uint4*>(Ab)[idx * 4 + j] = o;
        }
    }
}

// Pure bf16 GEMM, split-K bf16 partials + fused last-block reduction.
// Core is byte-identical to the twice-measured R7/R12 artifact:
// 128x128 block tile, BK=64, 256 threads = 4 waves (2x2), wave tile
// 64x64 via 4x4 of mfma_f32_16x16x32_bf16; global_load_lds 16B chunks,
// double-buffered, prefetch-dist-1, __syncthreads edges (measured best);
// LDS XOR swizzle slot = row*8 + (c ^ (row&7)), zero conflicts measured;
// swizzle inverse on per-lane SOURCE addr, linear LDS dest (contract).
// Epilogue (R14): store partials; __threadfence() (release: drains
// stores, writes back L2 so other XCDs can see them — G16 contract);
// __syncthreads; tid0 atomicAdd on per-tile counter (device-scope, m20);
// last arriver acquire-fences (invalidates local L2 -> reads fresh
// partials from LLC) and sums all 4 z-planes in fp32 -> out. Math is
// bit-identical to the old reduce_k. 512 fences+atomics total — NOT
// R3's per-element atomic storm.
__global__ __launch_bounds__(256, 2) void gemm_fused(
    const unsigned short* __restrict__ Am,  // [BATCH][KDIM] bf16 bits
    const unsigned short* __restrict__ Bm,  // [OSZ][KDIM] bf16 bits
    unsigned short* __restrict__ Cp,        // [SPLITK][M][N] bf16 partials
    float* __restrict__ Out,                // [M][N] fp32
    int* __restrict__ cnt,                  // [NTILES] arrival counters
    int M, int N, int K)
{
    __shared__ __align__(16) unsigned short As[2][TM * BK];   // 2 x 16 KB
    __shared__ __align__(16) unsigned short Bs[2][TN * BK];   // 2 x 16 KB

    const int tid  = threadIdx.x;
    const int wave = tid >> 6;
    const int lane = tid & 63;
    const int wm   = (wave >> 1) * 64;      // wave row offset in tile
    const int wn   = (wave & 1) * 64;       // wave col offset in tile

    const size_t baseA = (size_t)blockIdx.x * TM * K;
    const size_t baseB = (size_t)blockIdx.y * TN * K;
    const int kper  = K / SPLITK;           // 1024
    const int kbeg  = blockIdx.z * kper;
    const int niter = kper / BK;            // 16

    f32x4 acc[4][4] = {};

    const int mrow = lane & 15;             // m within 16x16 tile
    const int kc   = lane >> 4;             // 16B-chunk column offset within k

    // Staging: 128x64 bf16 = 16 KB = 1024 chunks of 16B; 256 thr x 4 its.
    auto stage = [&](const unsigned short* __restrict__ G, size_t gbase,
                     unsigned short* lds, int k0) {
        #pragma unroll
        for (int it = 0; it < 4; ++it) {
            int s    = it * 256 + tid;
            int row  = s >> 3;
            int csrc = (s & 7) ^ (row & 7);
            const unsigned short* g = G + gbase + (size_t)row * K + k0 + csrc * 8;
            unsigned short* l = lds + (size_t)(it * 256 + wave * 64) * 8;
            __builtin_amdgcn_global_load_lds(
                (const __attribute__((address_space(1))) uint32_t*)g,
                (__attribute__((address_space(3))) uint32_t*)l, 16, 0, 0);
        }
    };

    stage(Bm, baseB, &Bs[0][0], kbeg);
    stage(Am, baseA, &As[0][0], kbeg);
    __syncthreads();

    for (int kt = 0; kt < niter; ++kt) {
        const int k0 = kbeg + kt * BK;
        const int p  = kt & 1;
        if (kt + 1 < niter) {
            stage(Bm, baseB, &Bs[1 - p][0], k0 + BK);  // async, flies through
            stage(Am, baseA, &As[1 - p][0], k0 + BK);  // the MFMA phase
        }

        const unsigned short* Ap = &As[p][0];
        const unsigned short* Bp = &Bs[p][0];
        #pragma unroll
        for (int ks = 0; ks < BK; ks += 32) {
            bf16x8 aF[4], bF[4];
            const int cbase = (ks >> 3) + kc;
            #pragma unroll
            for (int mi = 0; mi < 4; ++mi) {
                int r = wm + mi * 16 + mrow;
                int slot = r * 8 + (cbase ^ (r & 7));
                aF[mi] = *reinterpret_cast<const bf16x8*>(Ap + (size_t)slot * 8);
            }
            #pragma unroll
            for (int ni = 0; ni < 4; ++ni) {
                int r = wn + ni * 16 + mrow;
                int slot = r * 8 + (cbase ^ (r & 7));
                bF[ni] = *reinterpret_cast<const bf16x8*>(Bp + (size_t)slot * 8);
            }
            #pragma unroll
            for (int mi = 0; mi < 4; ++mi)
                #pragma unroll
                for (int ni = 0; ni < 4; ++ni)
                    acc[mi][ni] = __builtin_amdgcn_mfma_f32_16x16x32_bf16(
                        aF[mi], bF[ni], acc[mi][ni], 0, 0, 0);
        }
        __syncthreads();   // completes buf[1-p] stage; fences buf[p] reuse
    }

    // bf16 partials, plain stores (no atomics).
    // C/D layout (m89-verified): col = lane&15, row = (lane>>4)*4 + r
    unsigned short* Cz = Cp + (size_t)blockIdx.z * M * N;
    const int orow = blockIdx.x * TM + wm + (lane >> 4) * 4;
    const int ocol = blockIdx.y * TN + wn + (lane & 15);
    #pragma unroll
    for (int mi = 0; mi < 4; ++mi)
        #pragma unroll
        for (int ni = 0; ni < 4; ++ni)
            #pragma unroll
            for (int r = 0; r < 4; ++r)
                Cz[(size_t)(orow + mi * 16 + r) * N + ocol + ni * 16] =
                    f2bf(acc[mi][ni][r]);

    // ---- fused split-K reduction (threadfence-reduction pattern) ----
    __threadfence();                       // release: partials visible
    __syncthreads();                       // all threads' stores issued
    __shared__ int sPrev;
    const int tileId = blockIdx.x * NTILEY + blockIdx.y;
    if (tid == 0) sPrev = atomicAdd(&cnt[tileId], 1);
    __syncthreads();
    if (sPrev == SPLITK - 1) {             // last arriver reduces
        __threadfence();                   // acquire: see others' partials
        const int row0 = blockIdx.x * TM;
        const int col0 = blockIdx.y * TN;
        // 128x128 tile, 256 threads: thread t covers rows (t>>4)+16*rr,
        // cols (t&15)*8 .. +7. 16 consecutive threads read 256B/row.
        #pragma unroll
        for (int rr = 0; rr < 8; ++rr) {
            const int row = (tid >> 4) + rr * 16;
            const int col = (tid & 15) * 8;
            const size_t off = (size_t)(row0 + row) * N + col0 + col;
            float s[8] = {};
            #pragma unroll
            for (int z = 0; z < SPLITK; ++z) {
                uint4 v = *reinterpret_cast<const uint4*>(
                    Cp + (size_t)z * M * N + off);
                s[0] += __uint_as_float((v.x & 0xFFFFu) << 16);
                s[1] += __uint_as_float(v.x & 0xFFFF0000u);
                s[2] += __uint_as_float((v.y & 0xFFFFu) << 16);
                s[3] += __uint_as_float(v.y & 0xFFFF0000u);
                s[4] += __uint_as_float((v.z & 0xFFFFu) << 16);
                s[5] += __uint_as_float(v.z & 0xFFFF0000u);
                s[6] += __uint_as_float((v.w & 0xFFFFu) << 16);
                s[7] += __uint_as_float(v.w & 0xFFFF0000u);
            }
            float4 o0 = {s[0], s[1], s[2], s[3]};
            float4 o1 = {s[4], s[5], s[6], s[7]};
            *reinterpret_cast<float4*>(Out + off)     = o0;
            *reinterpret_cast<float4*>(Out + off + 4) = o1;
        }
    }
}

extern "C" void kernel_launch(void* const* d_in, const int* in_sizes, int n_in,
                              void* d_out, int out_size, void* d_ws, size_t ws_size,
                              hipStream_t stream)
{
    const float* x    = (const float*)d_in[0];   // [4096][512]
    const float* coef = (const float*)d_in[1];   // [512][512][8]
    float* out = (float*)d_out;                  // [4096][512]

    // workspace: bf16 partials [SPLITK][4096][512] (16.8 MB)
    //          + coef bf16 [512][4096]             (4.2 MB)
    //          + A bf16 [4096][4096]               (33.5 MB)
    //          + int counters [128]                (512 B)
    unsigned short* part  = (unsigned short*)d_ws;
    unsigned short* coefb = part  + (size_t)SPLITK * BATCH * OSZ;
    unsigned short* Ab    = coefb + (size_t)OSZ * KDIM;
    int*            cnt   = (int*)(Ab + (size_t)BATCH * KDIM);

    prep<<<NB_CONV + NB_JAC, 256, 0, stream>>>(coef, coefb, x, Ab, cnt);

    dim3 grid(BATCH / TM, OSZ / TN, SPLITK);     // 32 x 4 x 4 = 512 blocks
    gemm_fused<<<grid, 256, 0, stream>>>(Ab, coefb, part, out, cnt,
                                         BATCH, OSZ, KDIM);
}

// Round 13
// 102.519 us; speedup vs baseline: 1.7187x; 1.7187x over previous
//
#include <hip/hip_runtime.h>
#include <stdint.h>

// Problem constants (from reference setup_inputs)
#define BATCH 4096
#define ISZ   512
#define OSZ   512
#define KDIM  4096           // contraction dim: k = i*8 + d

// GEMM tiling (R15 = R12/R7 revert: 128x128 tile, BK=64, 256 thr,
// 2 blk/CU, __syncthreads edges, separate reduce_k dispatch).
// Full history: R7/R12 (identical source) measured 96.0 AND 101.8 ->
// noise band +-3us. R8 8-phase (108.6), R10 pipelined (104.5), R11
// counted-vmcnt (103.2): schedule surgery never beat noise (m131-m141:
// 2-blk/CU implicit overlap already hides the drain). R13 32x32x16 core
// (103.7): matrix-pipe cycles not binding. R14 fused threadfence-
// reduction (176.2!): __threadfence release = buffer_wbl2 L2 writeback
// x512 blocks -> TCC serialization, gemm 30->105us, MfmaUtil 6%. On
// MI355X cross-XCD fences are us-class; the separate reduce_k dispatch
// IS the cheap sync. This file is the twice-measured best artifact.
#define TM 128
#define TN 128
#define BK 64
#define SPLITK 4

typedef __bf16 bf16x8 __attribute__((ext_vector_type(8)));
typedef float  f32x4  __attribute__((ext_vector_type(4)));

__device__ __forceinline__ unsigned short f2bf(float f) {
    uint32_t u = __float_as_uint(f);
    u = (u + 0x7FFFu + ((u >> 16) & 1u)) >> 16;
    return (unsigned short)u;
}

// prep: blocks [0,2048) coef fp32 [O][I][D] -> bf16 [O][K] (k-contiguous);
// blocks [2048,4096): jacobi8(tanh(x)) -> A bf16 [BATCH][KDIM], 4 x/thread.
// Jacobi computed ONCE (R7 win: in-gemm recompute was the bottleneck).
#define NB_CONV 2048         // (OSZ*KDIM/4) / 256
#define NB_JAC  2048         // (BATCH*ISZ/4) / 256
__global__ __launch_bounds__(256) void prep(
    const float* __restrict__ coef, unsigned short* __restrict__ coefb,
    const float* __restrict__ X,    unsigned short* __restrict__ Ab)
{
    const int b = blockIdx.x;
    if (b < NB_CONV) {
        int idx = b * 256 + threadIdx.x;
        float4 v = reinterpret_cast<const float4*>(coef)[idx];
        uint2 o;
        o.x = (uint32_t)f2bf(v.x) | ((uint32_t)f2bf(v.y) << 16);
        o.y = (uint32_t)f2bf(v.z) | ((uint32_t)f2bf(v.w) << 16);
        reinterpret_cast<uint2*>(coefb)[idx] = o;
    } else {
        int idx = (b - NB_CONV) * 256 + threadIdx.x;   // over [BATCH*ISZ/4]
        float4 xv = reinterpret_cast<const float4*>(X)[idx];
        const float xs[4] = {xv.x, xv.y, xv.z, xv.w};
        #pragma unroll
        for (int j = 0; j < 4; ++j) {
            // tanh(x) = 1 - 2/(exp(2x)+1); err ~1e-6 << bf16 ulp
            float e  = __expf(2.0f * xs[j]);
            float t  = 1.0f - 2.0f * __builtin_amdgcn_rcpf(e + 1.0f);
            float p0 = 1.0f;
            float p1 = 2.0f * t;
            float p2 = (1.875f     * t) * p1 - 0.75f       * p0;
            float p3 = (1.8666667f * t) * p2 - 0.8f        * p1;
            float p4 = (1.875f     * t) * p3 - 0.83333333f * p2;
            float p5 = (1.8857143f * t) * p4 - 0.85714287f * p3;
            float p6 = (1.8958333f * t) * p5 - 0.875f      * p4;
            float p7 = (1.9047619f * t) * p6 - 0.88888889f * p5;
            uint4 o;
            o.x = (uint32_t)f2bf(p0) | ((uint32_t)f2bf(p1) << 16);
            o.y = (uint32_t)f2bf(p2) | ((uint32_t)f2bf(p3) << 16);
            o.z = (uint32_t)f2bf(p4) | ((uint32_t)f2bf(p5) << 16);
            o.w = (uint32_t)f2bf(p6) | ((uint32_t)f2bf(p7) << 16);
            reinterpret_cast<uint4*>(Ab)[idx * 4 + j] = o;
        }
    }
}

// Pure bf16 GEMM, split-K partials with plain stores.
// 128x128 block tile, BK=64, 256 threads = 4 waves (2x2), wave tile 64x64
// via 4x4 of mfma_f32_16x16x32_bf16 (layout verified R1-R5).
// Both A and B stage via global_load_lds (16B chunks), double-buffered,
// prefetch-distance-1: next tile's async loads fly through this tile's
// MFMA phase; the __syncthreads edge drains them (vmcnt(0)) — measured
// best for this occupancy (R8/R10/R11 counted-vmcnt variants all lost).
// LDS XOR swizzle: slot = row*8 + (c ^ (row&7)); global_load_lds keeps
// its wave-uniform-base + lane*16 dest contract (swizzle applied on the
// per-lane SOURCE address). SQ_LDS_BANK_CONFLICT == 0 measured R2-R7.
__global__ __launch_bounds__(256, 2) void gemm_fused(
    const unsigned short* __restrict__ Am,  // [BATCH][KDIM] bf16 bits
    const unsigned short* __restrict__ Bm,  // [OSZ][KDIM] bf16 bits
    unsigned short* __restrict__ Cp,        // [SPLITK][M][N] bf16 partials
    int M, int N, int K)
{
    __shared__ __align__(16) unsigned short As[2][TM * BK];   // 2 x 16 KB
    __shared__ __align__(16) unsigned short Bs[2][TN * BK];   // 2 x 16 KB

    const int tid  = threadIdx.x;
    const int wave = tid >> 6;
    const int lane = tid & 63;
    const int wm   = (wave >> 1) * 64;      // wave row offset in tile
    const int wn   = (wave & 1) * 64;       // wave col offset in tile

    const size_t baseA = (size_t)blockIdx.x * TM * K;
    const size_t baseB = (size_t)blockIdx.y * TN * K;
    const int kper  = K / SPLITK;           // 1024
    const int kbeg  = blockIdx.z * kper;
    const int niter = kper / BK;            // 16

    f32x4 acc[4][4] = {};

    const int mrow = lane & 15;             // m within 16x16 tile
    const int kc   = lane >> 4;             // 16B-chunk column offset within k

    // Staging: 128x64 bf16 = 16 KB = 1024 chunks of 16B; 256 thr x 4 its.
    // Dest chunk s is linear (wave-uniform base + lane*16); source col is
    // pre-swizzled so LDS chunk (row, sc) holds global col sc ^ (row&7).
    auto stage = [&](const unsigned short* __restrict__ G, size_t gbase,
                     unsigned short* lds, int k0) {
        #pragma unroll
        for (int it = 0; it < 4; ++it) {
            int s    = it * 256 + tid;
            int row  = s >> 3;
            int csrc = (s & 7) ^ (row & 7);
            const unsigned short* g = G + gbase + (size_t)row * K + k0 + csrc * 8;
            unsigned short* l = lds + (size_t)(it * 256 + wave * 64) * 8;
            __builtin_amdgcn_global_load_lds(
                (const __attribute__((address_space(1))) uint32_t*)g,
                (__attribute__((address_space(3))) uint32_t*)l, 16, 0, 0);
        }
    };

    stage(Bm, baseB, &Bs[0][0], kbeg);
    stage(Am, baseA, &As[0][0], kbeg);
    __syncthreads();

    for (int kt = 0; kt < niter; ++kt) {
        const int k0 = kbeg + kt * BK;
        const int p  = kt & 1;
        if (kt + 1 < niter) {
            stage(Bm, baseB, &Bs[1 - p][0], k0 + BK);  // async, flies through
            stage(Am, baseA, &As[1 - p][0], k0 + BK);  // the MFMA phase
        }

        const unsigned short* Ap = &As[p][0];
        const unsigned short* Bp = &Bs[p][0];
        #pragma unroll
        for (int ks = 0; ks < BK; ks += 32) {
            bf16x8 aF[4], bF[4];
            const int cbase = (ks >> 3) + kc;
            #pragma unroll
            for (int mi = 0; mi < 4; ++mi) {
                int r = wm + mi * 16 + mrow;
                int slot = r * 8 + (cbase ^ (r & 7));
                aF[mi] = *reinterpret_cast<const bf16x8*>(Ap + (size_t)slot * 8);
            }
            #pragma unroll
            for (int ni = 0; ni < 4; ++ni) {
                int r = wn + ni * 16 + mrow;
                int slot = r * 8 + (cbase ^ (r & 7));
                bF[ni] = *reinterpret_cast<const bf16x8*>(Bp + (size_t)slot * 8);
            }
            #pragma unroll
            for (int mi = 0; mi < 4; ++mi)
                #pragma unroll
                for (int ni = 0; ni < 4; ++ni)
                    acc[mi][ni] = __builtin_amdgcn_mfma_f32_16x16x32_bf16(
                        aF[mi], bF[ni], acc[mi][ni], 0, 0, 0);
        }
        __syncthreads();   // completes buf[1-p] stage; fences buf[p] reuse
    }

    // bf16 partials, plain stores (no atomics).
    // C/D layout (m89-verified): col = lane&15, row = (lane>>4)*4 + r
    unsigned short* Cz = Cp + (size_t)blockIdx.z * M * N;
    const int orow = blockIdx.x * TM + wm + (lane >> 4) * 4;
    const int ocol = blockIdx.y * TN + wn + (lane & 15);
    #pragma unroll
    for (int mi = 0; mi < 4; ++mi)
        #pragma unroll
        for (int ni = 0; ni < 4; ++ni)
            #pragma unroll
            for (int r = 0; r < 4; ++r)
                Cz[(size_t)(orow + mi * 16 + r) * N + ocol + ni * 16] =
                    f2bf(acc[mi][ni][r]);
}

// out = sum over SPLITK bf16 partials (fp32 accumulate), 8 outputs/thread
__global__ __launch_bounds__(256) void reduce_k(
    const unsigned short* __restrict__ part, float* __restrict__ out, int n8)
{
    int idx = blockIdx.x * 256 + threadIdx.x;
    if (idx >= n8) return;
    const uint4* p = reinterpret_cast<const uint4*>(part);   // 8 bf16 / uint4
    float s[8] = {};
    #pragma unroll
    for (int z = 0; z < SPLITK; ++z) {
        uint4 v = p[(size_t)z * n8 + idx];
        s[0] += __uint_as_float((v.x & 0xFFFFu) << 16);
        s[1] += __uint_as_float(v.x & 0xFFFF0000u);
        s[2] += __uint_as_float((v.y & 0xFFFFu) << 16);
        s[3] += __uint_as_float(v.y & 0xFFFF0000u);
        s[4] += __uint_as_float((v.z & 0xFFFFu) << 16);
        s[5] += __uint_as_float(v.z & 0xFFFF0000u);
        s[6] += __uint_as_float((v.w & 0xFFFFu) << 16);
        s[7] += __uint_as_float(v.w & 0xFFFF0000u);
    }
    float4 o0 = {s[0], s[1], s[2], s[3]};
    float4 o1 = {s[4], s[5], s[6], s[7]};
    reinterpret_cast<float4*>(out)[2 * idx]     = o0;
    reinterpret_cast<float4*>(out)[2 * idx + 1] = o1;
}

extern "C" void kernel_launch(void* const* d_in, const int* in_sizes, int n_in,
                              void* d_out, int out_size, void* d_ws, size_t ws_size,
                              hipStream_t stream)
{
    const float* x    = (const float*)d_in[0];   // [4096][512]
    const float* coef = (const float*)d_in[1];   // [512][512][8]
    float* out = (float*)d_out;                  // [4096][512]

    // workspace: bf16 partials [SPLITK][4096][512] (16.8 MB)
    //          + coef bf16 [512][4096]             (4.2 MB)
    //          + A bf16 [4096][4096]               (33.5 MB)
    unsigned short* part  = (unsigned short*)d_ws;
    unsigned short* coefb = part  + (size_t)SPLITK * BATCH * OSZ;
    unsigned short* Ab    = coefb + (size_t)OSZ * KDIM;

    prep<<<NB_CONV + NB_JAC, 256, 0, stream>>>(coef, coefb, x, Ab);

    dim3 grid(BATCH / TM, OSZ / TN, SPLITK);     // 32 x 4 x 4 = 512 blocks
    gemm_fused<<<grid, 256, 0, stream>>>(Ab, coefb, part, BATCH, OSZ, KDIM);

    int n8r = (BATCH * OSZ) / 8;                 // 262,144
    reduce_k<<<(n8r + 255) / 256, 256, 0, stream>>>(part, out, n8r);
}